// Round 2
// 325.959 us; speedup vs baseline: 1.0368x; 1.0368x over previous
//
#include <hip/hip_runtime.h>
#include <math.h>

#define SPU_ZERO 0.70710678118654752440f  // sqrt(0.5)

typedef float f4 __attribute__((ext_vector_type(4)));

// Branchless spu: spu(x) = x^2 - 0.5 for x >= 0, sigmoid(-x) - 1 for x < 0.
// Always computes both paths + selects; with ~50/50 random data the exec-masked
// version pays for both paths per wave anyway, so this removes branch/exec-mask
// overhead from the issue stream at no extra ALU cost.
__device__ __forceinline__ float spu_b(float v) {
    float e   = expf(v);                 // sigmoid(-v) = 1/(1+e^v)
    float s   = 1.0f / (1.0f + e);
    float neg = s - 1.0f;
    float pos = fmaf(v, v, -0.5f);
    return v >= 0.0f ? pos : neg;
}

__device__ __forceinline__ void spu_transform(float x, float l, float u,
                                              float& o, float& nl, float& nu) {
    float sl = spu_b(l);
    float su = spu_b(u);
    float slope   = (su - sl) / (u - l);        // width >= 1e-3, safe
    float chord_b = fmaf(-slope, l, sl);

    bool c1 = u <= 0.0f;       // case 1: entirely negative
    bool c2 = l >= 0.0f;       // case 2: entirely non-negative
    bool c3 = u >= SPU_ZERO;   // case 3 vs 4 discriminator (when straddling)

    // Tangent point: case 2 -> a2 (>=0); case 3 -> max(a2, SPU_ZERO) (>0).
    // For a >= 0: dspu(a) = 2a, spu(a) - a*dspu(a) = -a^2 - 0.5.
    float a2 = 0.5f * (u + l);
    float at = c2 ? a2 : fmaxf(a2, SPU_ZERO);
    float wt = at + at;
    float bt = fmaf(-at, at, -0.5f);

    // case 4 (straddle, 0 < u < sqrt(0.5))
    bool  flat4 = sl > su;
    float wu4 = flat4 ? 0.0f : slope;
    float bu4 = flat4 ? sl   : chord_b;         // max(sl,su) == sl when flat4

    bool tang = c2 || c3;
    float w_u = c1 ? 0.0f    : (c2 ? (u + l)            : (c3 ? slope   : wu4));
    float b_u = c1 ? sl      : (c2 ? fmaf(-u, l, 0.5f)  : (c3 ? chord_b : bu4));
    float w_l = c1 ? slope   : (tang ? wt : 0.0f);
    float b_l = c1 ? chord_b : (tang ? bt : -0.5f);

    o  = spu_b(x);
    nl = fmaf(w_l, l, b_l);
    nu = fmaf(w_u, u, b_u);
}

__device__ __forceinline__ void spu_transform4(f4 xv, f4 lv, f4 uv,
                                               f4& ov, f4& nlv, f4& nuv) {
#pragma unroll
    for (int k = 0; k < 4; ++k) {
        float o, nl, nu;
        spu_transform(xv[k], lv[k], uv[k], o, nl, nu);
        ov[k] = o; nlv[k] = nl; nuv[k] = nu;
    }
}

// 2x float4 per thread: 6 non-temporal loads issued back-to-back for MLP,
// branchless compute, 6 non-temporal stores. All data is strictly streaming
// (each byte touched exactly once) -> nt hints reduce L2/L3 churn.
__global__ void __launch_bounds__(256)
spu_kernel_v5(const f4* __restrict__ xs,
              const f4* __restrict__ ls,
              const f4* __restrict__ us,
              f4* __restrict__ out, int n4) {
    const int T = gridDim.x * blockDim.x;
    const int i = blockIdx.x * blockDim.x + threadIdx.x;
    if (i >= n4) return;

    const int  j  = i + T;
    const bool bj = j < n4;
    const int  jc = bj ? j : i;   // clamp so all 6 loads issue unconditionally

    f4 x0 = __builtin_nontemporal_load(xs + i);
    f4 l0 = __builtin_nontemporal_load(ls + i);
    f4 u0 = __builtin_nontemporal_load(us + i);
    f4 x1 = __builtin_nontemporal_load(xs + jc);
    f4 l1 = __builtin_nontemporal_load(ls + jc);
    f4 u1 = __builtin_nontemporal_load(us + jc);

    f4 o0, nl0, nu0, o1, nl1, nu1;
    spu_transform4(x0, l0, u0, o0, nl0, nu0);
    spu_transform4(x1, l1, u1, o1, nl1, nu1);

    __builtin_nontemporal_store(o0,  out + i);
    __builtin_nontemporal_store(nl0, out + n4 + i);
    __builtin_nontemporal_store(nu0, out + 2 * n4 + i);
    if (bj) {
        __builtin_nontemporal_store(o1,  out + j);
        __builtin_nontemporal_store(nl1, out + n4 + j);
        __builtin_nontemporal_store(nu1, out + 2 * n4 + j);
    }
}

__global__ void __launch_bounds__(64)
spu_kernel_tail(const float* __restrict__ xs,
                const float* __restrict__ ls,
                const float* __restrict__ us,
                float* __restrict__ out, int n, int start) {
    int i = start + blockIdx.x * blockDim.x + threadIdx.x;
    if (i >= n) return;
    float o, nl, nu;
    spu_transform(xs[i], ls[i], us[i], o, nl, nu);
    out[i]         = o;
    out[n + i]     = nl;
    out[2 * n + i] = nu;
}

extern "C" void kernel_launch(void* const* d_in, const int* in_sizes, int n_in,
                              void* d_out, int out_size, void* d_ws, size_t ws_size,
                              hipStream_t stream) {
    const float* x = (const float*)d_in[0];
    const float* l = (const float*)d_in[1];
    const float* u = (const float*)d_in[2];
    float* out = (float*)d_out;
    int n  = in_sizes[0];
    int n4 = n / 4;
    int rem = n - n4 * 4;

    if (n4 > 0) {
        // 2 float4 per thread
        int blocks = (n4 + 2 * 256 - 1) / (2 * 256);
        spu_kernel_v5<<<blocks, 256, 0, stream>>>(
            (const f4*)x, (const f4*)l, (const f4*)u, (f4*)out, n4);
    }
    if (rem > 0) {
        // only reachable when n % 4 != 0 (never for the expected N)
        spu_kernel_tail<<<1, 64, 0, stream>>>(x, l, u, out, n, n4 * 4);
    }
}

// Round 3
// 322.598 us; speedup vs baseline: 1.0476x; 1.0104x over previous
//
#include <hip/hip_runtime.h>
#include <math.h>

#define SPU_ZERO 0.70710678118654752440f  // sqrt(0.5)

typedef float f4 __attribute__((ext_vector_type(4)));

// Fast approximate reciprocal: v_rcp_f32, ~1 ulp. absmax tolerance is 0.125,
// so approximate rcp/exp are numerically free here.
__device__ __forceinline__ float frcp(float v) {
    return __builtin_amdgcn_rcpf(v);
}

// Branchless spu: spu(x) = x^2 - 0.5 for x >= 0, sigmoid(-x) - 1 for x < 0.
// __expf -> v_exp_f32 (2 instr vs ~18 for libm expf); rcp -> v_rcp_f32
// (1 instr vs ~10 for IEEE div). Select instead of branch.
__device__ __forceinline__ float spu_b(float v) {
    float e   = __expf(v);               // sigmoid(-v) = 1/(1+e^v)
    float s   = frcp(1.0f + e);
    float neg = s - 1.0f;
    float pos = fmaf(v, v, -0.5f);
    return v >= 0.0f ? pos : neg;
}

__device__ __forceinline__ void spu_transform(float x, float l, float u,
                                              float& o, float& nl, float& nu) {
    float sl = spu_b(l);
    float su = spu_b(u);
    float slope   = (su - sl) * frcp(u - l);    // width >= 1e-3, safe
    float chord_b = fmaf(-slope, l, sl);

    bool c1 = u <= 0.0f;       // case 1: entirely negative
    bool c2 = l >= 0.0f;       // case 2: entirely non-negative
    bool c3 = u >= SPU_ZERO;   // case 3 vs 4 discriminator (when straddling)

    // Tangent point: case 2 -> a2 (>=0); case 3 -> max(a2, SPU_ZERO) (>0).
    // For a >= 0: dspu(a) = 2a, spu(a) - a*dspu(a) = -a^2 - 0.5.
    float a2 = 0.5f * (u + l);
    float at = c2 ? a2 : fmaxf(a2, SPU_ZERO);
    float wt = at + at;
    float bt = fmaf(-at, at, -0.5f);

    // case 4 (straddle, 0 < u < sqrt(0.5))
    bool  flat4 = sl > su;
    float wu4 = flat4 ? 0.0f : slope;
    float bu4 = flat4 ? sl   : chord_b;         // max(sl,su) == sl when flat4

    bool tang = c2 || c3;
    float w_u = c1 ? 0.0f    : (c2 ? (u + l)            : (c3 ? slope   : wu4));
    float b_u = c1 ? sl      : (c2 ? fmaf(-u, l, 0.5f)  : (c3 ? chord_b : bu4));
    float w_l = c1 ? slope   : (tang ? wt : 0.0f);
    float b_l = c1 ? chord_b : (tang ? bt : -0.5f);

    o  = spu_b(x);
    nl = fmaf(w_l, l, b_l);
    nu = fmaf(w_u, u, b_u);
}

__device__ __forceinline__ void spu_transform4(f4 xv, f4 lv, f4 uv,
                                               f4& ov, f4& nlv, f4& nuv) {
#pragma unroll
    for (int k = 0; k < 4; ++k) {
        float o, nl, nu;
        spu_transform(xv[k], lv[k], uv[k], o, nl, nu);
        ov[k] = o; nlv[k] = nl; nuv[k] = nu;
    }
}

// 2x float4 per thread: 6 non-temporal loads issued back-to-back for MLP,
// branchless compute, 6 non-temporal stores. All data is strictly streaming
// (each byte touched exactly once) -> nt hints reduce L2/L3 churn.
__global__ void __launch_bounds__(256)
spu_kernel_v6(const f4* __restrict__ xs,
              const f4* __restrict__ ls,
              const f4* __restrict__ us,
              f4* __restrict__ out, int n4) {
    const int T = gridDim.x * blockDim.x;
    const int i = blockIdx.x * blockDim.x + threadIdx.x;
    if (i >= n4) return;

    const int  j  = i + T;
    const bool bj = j < n4;
    const int  jc = bj ? j : i;   // clamp so all 6 loads issue unconditionally

    f4 x0 = __builtin_nontemporal_load(xs + i);
    f4 l0 = __builtin_nontemporal_load(ls + i);
    f4 u0 = __builtin_nontemporal_load(us + i);
    f4 x1 = __builtin_nontemporal_load(xs + jc);
    f4 l1 = __builtin_nontemporal_load(ls + jc);
    f4 u1 = __builtin_nontemporal_load(us + jc);

    f4 o0, nl0, nu0, o1, nl1, nu1;
    spu_transform4(x0, l0, u0, o0, nl0, nu0);
    spu_transform4(x1, l1, u1, o1, nl1, nu1);

    __builtin_nontemporal_store(o0,  out + i);
    __builtin_nontemporal_store(nl0, out + n4 + i);
    __builtin_nontemporal_store(nu0, out + 2 * n4 + i);
    if (bj) {
        __builtin_nontemporal_store(o1,  out + j);
        __builtin_nontemporal_store(nl1, out + n4 + j);
        __builtin_nontemporal_store(nu1, out + 2 * n4 + j);
    }
}

__global__ void __launch_bounds__(64)
spu_kernel_tail(const float* __restrict__ xs,
                const float* __restrict__ ls,
                const float* __restrict__ us,
                float* __restrict__ out, int n, int start) {
    int i = start + blockIdx.x * blockDim.x + threadIdx.x;
    if (i >= n) return;
    float o, nl, nu;
    spu_transform(xs[i], ls[i], us[i], o, nl, nu);
    out[i]         = o;
    out[n + i]     = nl;
    out[2 * n + i] = nu;
}

extern "C" void kernel_launch(void* const* d_in, const int* in_sizes, int n_in,
                              void* d_out, int out_size, void* d_ws, size_t ws_size,
                              hipStream_t stream) {
    const float* x = (const float*)d_in[0];
    const float* l = (const float*)d_in[1];
    const float* u = (const float*)d_in[2];
    float* out = (float*)d_out;
    int n  = in_sizes[0];
    int n4 = n / 4;
    int rem = n - n4 * 4;

    if (n4 > 0) {
        // 2 float4 per thread
        int blocks = (n4 + 2 * 256 - 1) / (2 * 256);
        spu_kernel_v6<<<blocks, 256, 0, stream>>>(
            (const f4*)x, (const f4*)l, (const f4*)u, (f4*)out, n4);
    }
    if (rem > 0) {
        // only reachable when n % 4 != 0 (never for the expected N)
        spu_kernel_tail<<<1, 64, 0, stream>>>(x, l, u, out, n, n4 * 4);
    }
}